// Round 13
// baseline (59.146 us; speedup 1.0000x reference)
//
#include <hip/hip_runtime.h>
#include <math.h>

#define NQ 10
#define DIM 1024
#define HID 64
#define NT 64

template<int CTRL>
__device__ __forceinline__ float fdpp(float v) {
    return __int_as_float(__builtin_amdgcn_update_dpp(
        0, __float_as_int(v), CTRL, 0xF, 0xF, true));
}
__device__ __forceinline__ float bperm(int a4, float v) {
    return __int_as_float(__builtin_amdgcn_ds_bpermute(a4, __float_as_int(v)));
}

// fused RY*RX 2x2 complex gate (validated r4/r6/r12)
__device__ __forceinline__ void l1pair(float4 g, float& r0, float& i0, float& r1, float& i1) {
    float n0r = g.x * r0 - g.y * i0 - g.z * r1 + g.w * i1;
    float n0i = g.x * i0 + g.y * r0 - g.z * i1 - g.w * r1;
    float n1r = g.z * r0 + g.w * i0 + g.x * r1 + g.y * i1;
    float n1i = g.z * i0 - g.w * r0 + g.x * i1 - g.y * r1;
    r0 = n0r; i0 = n0i; r1 = n1r; i1 = n1i;
}
__device__ __forceinline__ void l2pair(float2 g, float& r0, float& i0, float& r1, float& i1) {
    float n0r = g.x * r0 - g.y * r1, n0i = g.x * i0 - g.y * i1;
    float n1r = g.y * r0 + g.x * r1, n1i = g.y * i0 + g.x * i1;
    r0 = n0r; i0 = n0i; r1 = n1r; i1 = n1i;
}

// lane gates: coefficients computed once, applied to BOTH rows' arrays
template<int P>
__device__ __forceinline__ void lane_gate_l1(float4 g, int lane,
        float (&vr0)[16], float (&vi0)[16], float (&vr1)[16], float (&vi1)[16]) {
    const float fsb = ((lane >> P) & 1) ? 1.f : -1.f;
    const float Bs = fsb * g.y, Cs = fsb * g.z;
    const int a4 = (lane ^ (1 << P)) << 2;
    #pragma unroll
    for (int r = 0; r < 16; r++) {
        float ur0, ui0, ur1, ui1;
        if constexpr (P == 0) {
            ur0 = fdpp<0xB1>(vr0[r]); ui0 = fdpp<0xB1>(vi0[r]);
            ur1 = fdpp<0xB1>(vr1[r]); ui1 = fdpp<0xB1>(vi1[r]);
        } else if constexpr (P == 1) {
            ur0 = fdpp<0x4E>(vr0[r]); ui0 = fdpp<0x4E>(vi0[r]);
            ur1 = fdpp<0x4E>(vr1[r]); ui1 = fdpp<0x4E>(vi1[r]);
        } else {
            ur0 = bperm(a4, vr0[r]); ui0 = bperm(a4, vi0[r]);
            ur1 = bperm(a4, vr1[r]); ui1 = bperm(a4, vi1[r]);
        }
        float nr0 = g.x * vr0[r] + Bs * vi0[r] + Cs * ur0 + g.w * ui0;
        float ni0 = g.x * vi0[r] - Bs * vr0[r] + Cs * ui0 - g.w * ur0;
        float nr1 = g.x * vr1[r] + Bs * vi1[r] + Cs * ur1 + g.w * ui1;
        float ni1 = g.x * vi1[r] - Bs * vr1[r] + Cs * ui1 - g.w * ur1;
        vr0[r] = nr0; vi0[r] = ni0; vr1[r] = nr1; vi1[r] = ni1;
    }
}
template<int P>
__device__ __forceinline__ void lane_gate_l2(float2 g, int lane,
        float (&vr0)[16], float (&vi0)[16], float (&vr1)[16], float (&vi1)[16]) {
    const float fsb = ((lane >> P) & 1) ? 1.f : -1.f;
    const float ssf = fsb * g.y;
    const int a4 = (lane ^ (1 << P)) << 2;
    #pragma unroll
    for (int r = 0; r < 16; r++) {
        float ur0, ui0, ur1, ui1;
        if constexpr (P == 0) {
            ur0 = fdpp<0xB1>(vr0[r]); ui0 = fdpp<0xB1>(vi0[r]);
            ur1 = fdpp<0xB1>(vr1[r]); ui1 = fdpp<0xB1>(vi1[r]);
        } else if constexpr (P == 1) {
            ur0 = fdpp<0x4E>(vr0[r]); ui0 = fdpp<0x4E>(vi0[r]);
            ur1 = fdpp<0x4E>(vr1[r]); ui1 = fdpp<0x4E>(vi1[r]);
        } else {
            ur0 = bperm(a4, vr0[r]); ui0 = bperm(a4, vi0[r]);
            ur1 = bperm(a4, vr1[r]); ui1 = bperm(a4, vi1[r]);
        }
        vr0[r] = g.x * vr0[r] + ssf * ur0;
        vi0[r] = g.x * vi0[r] + ssf * ui0;
        vr1[r] = g.x * vr1[r] + ssf * ur1;
        vi1[r] = g.x * vi1[r] + ssf * ui1;
    }
}

// ---- obs partials for BOTH rows: one address computation, second row's LDS
// read is the same vaddr + imm offset 8192 (row-1 slice). Math = r6/r12. ----
template<int HB, int CM>
__device__ __forceinline__ void obs_halved2(
        const float (&vr0)[16], const float (&vi0)[16],
        const float (&vr1)[16], const float (&vi1)[16],
        const char* stb, int base_cx, int w1, float& p0, float& p1) {
    float a0 = 0.f, b0 = 0.f, a1 = 0.f, b1 = 0.f;
    #pragma unroll
    for (int idx = 0; idx < 8; idx++) {
        const int lo = idx & ((1 << HB) - 1);
        const int r  = ((idx >> HB) << (HB + 1)) | lo;      // compile-time
        const int off = base_cx ^ (r << 9);                 // 1 VALU, shared
        const float2 c0 = *(const float2*)(stb + off);
        const float2 c1 = *(const float2*)(stb + 8192 + off);
        float t0, t1;
        if constexpr (CM) { t0 = vr0[r] * c0.y - vi0[r] * c0.x;
                            t1 = vr1[r] * c1.y - vi1[r] * c1.x; }
        else              { t0 = vr0[r] * c0.x + vi0[r] * c0.y;
                            t1 = vr1[r] * c1.x + vi1[r] * c1.y; }
        const float cf = __int_as_float(0x40000000 | (((w1 >> r) & 1) << 31));
        if (idx & 1) { b0 = fmaf(cf, t0, b0); b1 = fmaf(cf, t1, b1); }
        else         { a0 = fmaf(cf, t0, a0); a1 = fmaf(cf, t1, a1); }
    }
    p0 = a0 + b0; p1 = a1 + b1;
}
template<int CM>
__device__ __forceinline__ void obs_full2(
        const float (&vr0)[16], const float (&vi0)[16],
        const float (&vr1)[16], const float (&vi1)[16],
        const char* stb, int base_c, int w1, float& p0, float& p1) {
    float a0 = 0.f, b0 = 0.f, a1 = 0.f, b1 = 0.f;
    #pragma unroll
    for (int r = 0; r < 16; r++) {
        const float2 c0 = *(const float2*)(stb + base_c + (r << 9));
        const float2 c1 = *(const float2*)(stb + 8192 + base_c + (r << 9));
        float t0, t1;
        if constexpr (CM) { t0 = vr0[r] * c0.y - vi0[r] * c0.x;
                            t1 = vr1[r] * c1.y - vi1[r] * c1.x; }
        else              { t0 = vr0[r] * c0.x + vi0[r] * c0.y;
                            t1 = vr1[r] * c1.x + vi1[r] * c1.y; }
        const float cf = __int_as_float(0x3F800000 | (((w1 >> r) & 1) << 31));
        if (r & 1) { b0 = fmaf(cf, t0, b0); b1 = fmaf(cf, t1, b1); }
        else       { a0 = fmaf(cf, t0, a0); a1 = fmaf(cf, t1, a1); }
    }
    p0 = a0 + b0; p1 = a1 + b1;
}
__device__ __forceinline__ void obs_diag2(
        const float (&vr0)[16], const float (&vi0)[16],
        const float (&vr1)[16], const float (&vi1)[16],
        int w1, float& p0, float& p1) {
    float a0 = 0.f, b0 = 0.f, a1 = 0.f, b1 = 0.f;
    #pragma unroll
    for (int r = 0; r < 16; r++) {
        float t0 = fmaf(vr0[r], vr0[r], vi0[r] * vi0[r]);
        float t1 = fmaf(vr1[r], vr1[r], vi1[r] * vi1[r]);
        const float cf = __int_as_float(0x3F800000 | (((w1 >> r) & 1) << 31));
        if (r & 1) { b0 = fmaf(cf, t0, b0); b1 = fmaf(cf, t1, b1); }
        else       { a0 = fmaf(cf, t0, a0); a1 = fmaf(cf, t1, a1); }
    }
    p0 = a0 + b0; p1 = a1 + b1;
}

// 2 rows per wave: shared setup/decode/addressing, 2 independent dep chains.
// (64,2) caps VGPR at 256 (grid is 4 waves/CU, VGPR can't bind occupancy).
__global__ __launch_bounds__(NT, 2) void qsa_kernel(
    const float* __restrict__ x,
    const float* __restrict__ rx0,
    const float* __restrict__ ry0,
    const float* __restrict__ ry1,
    const int*   __restrict__ op_codes,
    float* __restrict__ out)
{
    __shared__ float2 st[2 * DIM];          // row0 at +0, row1 at +1024 (+8192 B)
    __shared__ float  cb[2][64 * 17];       // transpose-reduce buffers
    __shared__ float4 s_l1[NQ];
    __shared__ float2 s_l2[NQ];
    __shared__ int4   s_meta[HID];          // xm, yzm&63, w1, hbc|cm<<3

    const int lane = threadIdx.x;
    const int row0 = blockIdx.x * 2;        // rows = 2048, grid = 1024

    // ---- setup tables (r12 verbatim) ----
    if (lane < NQ) {
        float a = 0.5f * rx0[lane], b = 0.5f * ry0[lane];
        float c1 = cosf(a), s1 = sinf(a), c2 = cosf(b), s2 = sinf(b);
        s_l1[lane] = make_float4(c1 * c2, s1 * s2, s2 * c1, c2 * s1);  // A,B,C,D
    } else if (lane < 2 * NQ) {
        float a = 0.5f * ry1[lane - NQ];
        s_l2[lane - NQ] = make_float2(cosf(a), sinf(a));
    }
    {
        const int o = lane;                 // lane o builds meta for obs o
        int xm = 0, yzm = 0, ny = 0;
        #pragma unroll
        for (int q = 0; q < NQ; q++) {
            int code = op_codes[o * NQ + q];
            int bit  = 1 << (NQ - 1 - q);       // qubit q = element bit 9-q
            if (code == 1) xm |= bit;
            else if (code == 2) { xm |= bit; yzm |= bit; ny++; }
            else if (code == 3) yzm |= bit;
        }
        const int cm = ny & 1, gflip = (ny >> 1) & 1;
        const int yh = yzm >> 6;
        int w1 = 0;
        #pragma unroll
        for (int r = 0; r < 16; r++)
            w1 |= ((__popc(r & yh) & 1) ^ gflip) << r;
        const int xmr = (xm >> 6) & 15;
        int hbc;
        if (xm == 0)      hbc = 5;              // diagonal
        else if (xmr)     hbc = __ffs(xmr) - 1; // halved on reg bit 0..3
        else              hbc = 4;              // lane-only xm: full 16
        s_meta[o] = make_int4(xm, yzm & 63, w1, hbc | (cm << 3));
    }

    // ---- load + normalize both rows (independent chains) ----
    float vr0[16], vi0[16], vr1[16], vi1[16];
    {
        const float* xr = x + (size_t)row0 * DIM;
        float ssq0 = 0.f, ssq1 = 0.f;
        #pragma unroll
        for (int r = 0; r < 16; r++) {
            vr0[r] = xr[(r << 6) + lane];
            vr1[r] = xr[DIM + (r << 6) + lane];
            vi0[r] = 0.f; vi1[r] = 0.f;
            ssq0 += vr0[r] * vr0[r];
            ssq1 += vr1[r] * vr1[r];
        }
        #pragma unroll
        for (int off = 32; off; off >>= 1) {
            ssq0 += __shfl_xor(ssq0, off, 64);
            ssq1 += __shfl_xor(ssq1, off, 64);
        }
        const float inv0 = 1.0f / sqrtf(ssq0);
        const float inv1 = 1.0f / sqrtf(ssq1);
        #pragma unroll
        for (int r = 0; r < 16; r++) { vr0[r] *= inv0; vr1[r] *= inv1; }
    }

    __syncthreads();            // publish tables (1-wave block: near-free)

    // ---- layer 1: qubits 0..3 reg-bit gates, 4..9 lane-bit gates (r12) ----
    #pragma unroll
    for (int j = 0; j < 4; j++) {
        const float4 g = s_l1[j];
        const int m = 1 << (3 - j);
        #pragma unroll
        for (int r = 0; r < 16; r++)
            if (!(r & m)) {
                l1pair(g, vr0[r], vi0[r], vr0[r | m], vi0[r | m]);
                l1pair(g, vr1[r], vi1[r], vr1[r | m], vi1[r | m]);
            }
    }
    lane_gate_l1<5>(s_l1[4], lane, vr0, vi0, vr1, vi1);
    lane_gate_l1<4>(s_l1[5], lane, vr0, vi0, vr1, vi1);
    lane_gate_l1<3>(s_l1[6], lane, vr0, vi0, vr1, vi1);
    lane_gate_l1<2>(s_l1[7], lane, vr0, vi0, vr1, vi1);
    lane_gate_l1<1>(s_l1[8], lane, vr0, vi0, vr1, vi1);
    lane_gate_l1<0>(s_l1[9], lane, vr0, vi0, vr1, vi1);

    // ---- CNOT ring: composed permutation gather, both rows (wave-private) ----
    #pragma unroll
    for (int r = 0; r < 16; r++) {
        const int d = (r << 6) | lane;
        st[d]        = make_float2(vr0[r], vi0[r]);
        st[d + DIM]  = make_float2(vr1[r], vi1[r]);
    }
    #pragma unroll
    for (int r = 0; r < 16; r++) {
        const int d = (r << 6) | lane;
        const int src = (d ^ (d >> 1)) ^ ((d & 1) * 0x300);
        const float2 t0 = st[src];
        const float2 t1 = st[src + DIM];
        vr0[r] = t0.x; vi0[r] = t0.y;
        vr1[r] = t1.x; vi1[r] = t1.y;
    }

    // ---- layer 2 (RY) ----
    #pragma unroll
    for (int j = 0; j < 4; j++) {
        const float2 g = s_l2[j];
        const int m = 1 << (3 - j);
        #pragma unroll
        for (int r = 0; r < 16; r++)
            if (!(r & m)) {
                l2pair(g, vr0[r], vi0[r], vr0[r | m], vi0[r | m]);
                l2pair(g, vr1[r], vi1[r], vr1[r | m], vi1[r | m]);
            }
    }
    lane_gate_l2<5>(s_l2[4], lane, vr0, vi0, vr1, vi1);
    lane_gate_l2<4>(s_l2[5], lane, vr0, vi0, vr1, vi1);
    lane_gate_l2<3>(s_l2[6], lane, vr0, vi0, vr1, vi1);
    lane_gate_l2<2>(s_l2[7], lane, vr0, vi0, vr1, vi1);
    lane_gate_l2<1>(s_l2[8], lane, vr0, vi0, vr1, vi1);
    lane_gate_l2<0>(s_l2[9], lane, vr0, vi0, vr1, vi1);

    // ---- final-state mirrors (c-side source) ----
    #pragma unroll
    for (int r = 0; r < 16; r++) {
        const int d = (r << 6) | lane;
        st[d]       = make_float2(vr0[r], vi0[r]);
        st[d + DIM] = make_float2(vr1[r], vi1[r]);
    }

    // ---- observables: decode/address once per obs, both rows computed ----
    const char* stb = (const char*)st;
    float* cbw0 = &cb[0][lane * 17];
    float* cbw1 = &cb[1][lane * 17];
    const float* cbr0 = &cb[0][(lane >> 4) * (16 * 17) + (lane & 15)];
    const float* cbr1 = &cb[1][(lane >> 4) * (16 * 17) + (lane & 15)];
    float res0 = 0.f, res1 = 0.f;
    #pragma unroll 1
    for (int o = 0; o < HID; o++) {
        int4 mt = s_meta[o];
        const int xm   = __builtin_amdgcn_readfirstlane(mt.x);
        const int yzml = __builtin_amdgcn_readfirstlane(mt.y);
        const int w1   = __builtin_amdgcn_readfirstlane(mt.z);
        const int knd  = __builtin_amdgcn_readfirstlane(mt.w);
        const int hbc = knd & 7, cm = knd >> 3;
        float p0, p1;
        if (hbc == 5) {
            obs_diag2(vr0, vi0, vr1, vi1, w1, p0, p1);
        } else {
            const int xml = xm & 63, xmr = (xm >> 6) & 15;
            const int base_cx = (xmr << 9) | ((lane ^ xml) << 3);
            switch (hbc | (cm << 3)) {
                case 0:     obs_halved2<0,0>(vr0, vi0, vr1, vi1, stb, base_cx, w1, p0, p1); break;
                case 1:     obs_halved2<1,0>(vr0, vi0, vr1, vi1, stb, base_cx, w1, p0, p1); break;
                case 2:     obs_halved2<2,0>(vr0, vi0, vr1, vi1, stb, base_cx, w1, p0, p1); break;
                case 3:     obs_halved2<3,0>(vr0, vi0, vr1, vi1, stb, base_cx, w1, p0, p1); break;
                case 4:     obs_full2<0>(vr0, vi0, vr1, vi1, stb, base_cx, w1, p0, p1);     break;
                case 8 | 0: obs_halved2<0,1>(vr0, vi0, vr1, vi1, stb, base_cx, w1, p0, p1); break;
                case 8 | 1: obs_halved2<1,1>(vr0, vi0, vr1, vi1, stb, base_cx, w1, p0, p1); break;
                case 8 | 2: obs_halved2<2,1>(vr0, vi0, vr1, vi1, stb, base_cx, w1, p0, p1); break;
                case 8 | 3: obs_halved2<3,1>(vr0, vi0, vr1, vi1, stb, base_cx, w1, p0, p1); break;
                default:    obs_full2<1>(vr0, vi0, vr1, vi1, stb, base_cx, w1, p0, p1);     break;
            }
        }
        const int sl = (__popc(lane & yzml) & 1) << 31;
        p0 = __int_as_float(__float_as_int(p0) ^ sl);
        p1 = __int_as_float(__float_as_int(p1) ^ sl);
        cbw0[o & 15] = p0;                      // 1 LDS write each, no butterfly
        cbw1[o & 15] = p1;
        if ((o & 15) == 15) {                   // drain chunk of 16 obs (r6/r12)
            const int c = o >> 4;
            float s00 = 0.f, s01 = 0.f, s10 = 0.f, s11 = 0.f;
            #pragma unroll
            for (int k = 0; k < 16; k += 2) {
                s00 += cbr0[(k + 0) * 17];
                s01 += cbr0[(k + 1) * 17];
                s10 += cbr1[(k + 0) * 17];
                s11 += cbr1[(k + 1) * 17];
            }
            float tot0 = s00 + s01;
            float tot1 = s10 + s11;
            tot0 += __shfl_xor(tot0, 16, 64);
            tot1 += __shfl_xor(tot1, 16, 64);
            tot0 += __shfl_xor(tot0, 32, 64);
            tot1 += __shfl_xor(tot1, 32, 64);
            if ((lane >> 4) == c) { res0 = tot0; res1 = tot1; }
        }
    }
    out[(size_t)row0 * HID + lane]       = res0;
    out[(size_t)(row0 + 1) * HID + lane] = res1;
}

extern "C" void kernel_launch(void* const* d_in, const int* in_sizes, int n_in,
                              void* d_out, int out_size, void* d_ws, size_t ws_size,
                              hipStream_t stream) {
    const float* x   = (const float*)d_in[0];
    const float* rx0 = (const float*)d_in[1];
    const float* ry0 = (const float*)d_in[2];
    const float* ry1 = (const float*)d_in[3];
    const int*   op  = (const int*)d_in[4];
    float* o = (float*)d_out;
    const int rows = in_sizes[0] / DIM;    // B*T = 2048
    qsa_kernel<<<rows / 2, NT, 0, stream>>>(x, rx0, ry0, ry1, op, o);
}

// Round 14
// 47.024 us; speedup vs baseline: 1.2578x; 1.2578x over previous
//
#include <hip/hip_runtime.h>
#include <math.h>

#define NQ 10
#define DIM 1024
#define HID 64

template<int CTRL>
__device__ __forceinline__ float fdpp(float v) {
    return __int_as_float(__builtin_amdgcn_update_dpp(
        0, __float_as_int(v), CTRL, 0xF, 0xF, true));
}
__device__ __forceinline__ float bperm(int a4, float v) {
    return __int_as_float(__builtin_amdgcn_ds_bpermute(a4, __float_as_int(v)));
}

// fused RY*RX 2x2 complex gate (validated r4/r6/r12)
__device__ __forceinline__ void l1pair(float4 g, float& r0, float& i0, float& r1, float& i1) {
    float n0r = g.x * r0 - g.y * i0 - g.z * r1 + g.w * i1;
    float n0i = g.x * i0 + g.y * r0 - g.z * i1 - g.w * r1;
    float n1r = g.z * r0 + g.w * i0 + g.x * r1 + g.y * i1;
    float n1i = g.z * i0 - g.w * r0 + g.x * i1 - g.y * r1;
    r0 = n0r; i0 = n0i; r1 = n1r; i1 = n1i;
}
__device__ __forceinline__ void l2pair(float2 g, float& r0, float& i0, float& r1, float& i1) {
    float n0r = g.x * r0 - g.y * r1, n0i = g.x * i0 - g.y * i1;
    float n1r = g.y * r0 + g.x * r1, n1i = g.y * i0 + g.x * i1;
    r0 = n0r; i0 = n0i; r1 = n1r; i1 = n1i;
}

template<int P>
__device__ __forceinline__ void lane_gate_l1(float4 g, int lane, float (&vr)[16], float (&vi)[16]) {
    const float fsb = ((lane >> P) & 1) ? 1.f : -1.f;
    const float Bs = fsb * g.y, Cs = fsb * g.z;
    const int a4 = (lane ^ (1 << P)) << 2;
    #pragma unroll
    for (int r = 0; r < 16; r++) {
        float ur, ui;
        if constexpr (P == 0)      { ur = fdpp<0xB1>(vr[r]); ui = fdpp<0xB1>(vi[r]); }
        else if constexpr (P == 1) { ur = fdpp<0x4E>(vr[r]); ui = fdpp<0x4E>(vi[r]); }
        else                       { ur = bperm(a4, vr[r]);  ui = bperm(a4, vi[r]); }
        float nr = g.x * vr[r] + Bs * vi[r] + Cs * ur + g.w * ui;
        float ni = g.x * vi[r] - Bs * vr[r] + Cs * ui - g.w * ur;
        vr[r] = nr; vi[r] = ni;
    }
}
template<int P>
__device__ __forceinline__ void lane_gate_l2(float2 g, int lane, float (&vr)[16], float (&vi)[16]) {
    const float fsb = ((lane >> P) & 1) ? 1.f : -1.f;
    const float ssf = fsb * g.y;
    const int a4 = (lane ^ (1 << P)) << 2;
    #pragma unroll
    for (int r = 0; r < 16; r++) {
        float ur, ui;
        if constexpr (P == 0)      { ur = fdpp<0xB1>(vr[r]); ui = fdpp<0xB1>(vi[r]); }
        else if constexpr (P == 1) { ur = fdpp<0x4E>(vr[r]); ui = fdpp<0x4E>(vi[r]); }
        else                       { ur = bperm(a4, vr[r]);  ui = bperm(a4, vi[r]); }
        vr[r] = g.x * vr[r] + ssf * ur;
        vi[r] = g.x * vi[r] + ssf * ui;
    }
}

// ---- obs partial sums (validated r6/r12, verbatim) ----
template<int HB, int CM>
__device__ __forceinline__ float obs_halved(const float (&vr)[16], const float (&vi)[16],
                                            const char* stb, int base_cx, int w1) {
    float a0 = 0.f, a1 = 0.f;
    #pragma unroll
    for (int idx = 0; idx < 8; idx++) {
        const int lo = idx & ((1 << HB) - 1);
        const int r  = ((idx >> HB) << (HB + 1)) | lo;      // compile-time
        const float2 c = *(const float2*)(stb + (base_cx ^ (r << 9)));
        float t;
        if constexpr (CM) t = vr[r] * c.y - vi[r] * c.x;    // odd nY
        else              t = vr[r] * c.x + vi[r] * c.y;    // even nY
        const int cf = 0x40000000 | (((w1 >> r) & 1) << 31);
        if (idx & 1) a1 = fmaf(__int_as_float(cf), t, a1);
        else         a0 = fmaf(__int_as_float(cf), t, a0);
    }
    return a0 + a1;
}
template<int CM>
__device__ __forceinline__ float obs_full(const float (&vr)[16], const float (&vi)[16],
                                          const char* stb, int base_c, int w1) {
    float a0 = 0.f, a1 = 0.f;
    #pragma unroll
    for (int r = 0; r < 16; r++) {
        const float2 c = *(const float2*)(stb + base_c + (r << 9));
        float t;
        if constexpr (CM) t = vr[r] * c.y - vi[r] * c.x;
        else              t = vr[r] * c.x + vi[r] * c.y;
        const int cf = 0x3F800000 | (((w1 >> r) & 1) << 31);
        if (r & 1) a1 = fmaf(__int_as_float(cf), t, a1);
        else       a0 = fmaf(__int_as_float(cf), t, a0);
    }
    return a0 + a1;
}
__device__ __forceinline__ float obs_diag(const float (&vr)[16], const float (&vi)[16], int w1) {
    float a0 = 0.f, a1 = 0.f;
    #pragma unroll
    for (int r = 0; r < 16; r++) {
        float t = fmaf(vr[r], vr[r], vi[r] * vi[r]);
        const int cf = 0x3F800000 | (((w1 >> r) & 1) << 31);
        if (r & 1) a1 = fmaf(__int_as_float(cf), t, a1);
        else       a0 = fmaf(__int_as_float(cf), t, a0);
    }
    return a0 + a1;
}

// build s_meta[o] (r12 verbatim, one thread per o)
__device__ __forceinline__ int4 make_meta(const int* op_codes, int o) {
    int xm = 0, yzm = 0, ny = 0;
    #pragma unroll
    for (int q = 0; q < NQ; q++) {
        int code = op_codes[o * NQ + q];
        int bit  = 1 << (NQ - 1 - q);       // qubit q = element bit 9-q
        if (code == 1) xm |= bit;
        else if (code == 2) { xm |= bit; yzm |= bit; ny++; }
        else if (code == 3) yzm |= bit;
    }
    const int cm = ny & 1, gflip = (ny >> 1) & 1;
    const int yh = yzm >> 6;
    int w1 = 0;
    #pragma unroll
    for (int r = 0; r < 16; r++)
        w1 |= ((__popc(r & yh) & 1) ^ gflip) << r;
    const int xmr = (xm >> 6) & 15;
    int hbc;
    if (xm == 0)      hbc = 5;              // diagonal
    else if (xmr)     hbc = __ffs(xmr) - 1; // halved on reg bit 0..3
    else              hbc = 4;              // lane-only xm: full 16
    return make_int4(xm, yzm & 63, w1, hbc | (cm << 3));
}

// r12 obs body for one obs (validated): returns per-lane partial p
__device__ __forceinline__ float obs_one(int4 mt, int lane,
        const float (&vr)[16], const float (&vi)[16], const char* stb) {
    const int xm   = __builtin_amdgcn_readfirstlane(mt.x);
    const int yzml = __builtin_amdgcn_readfirstlane(mt.y);
    const int w1   = __builtin_amdgcn_readfirstlane(mt.z);
    const int knd  = __builtin_amdgcn_readfirstlane(mt.w);
    const int hbc = knd & 7, cm = knd >> 3;
    float p;
    if (hbc == 5) {
        p = obs_diag(vr, vi, w1);
    } else {
        const int xml = xm & 63, xmr = (xm >> 6) & 15;
        const int base_cx = (xmr << 9) | ((lane ^ xml) << 3);
        switch (hbc | (cm << 3)) {
            case 0:     p = obs_halved<0,0>(vr, vi, stb, base_cx, w1); break;
            case 1:     p = obs_halved<1,0>(vr, vi, stb, base_cx, w1); break;
            case 2:     p = obs_halved<2,0>(vr, vi, stb, base_cx, w1); break;
            case 3:     p = obs_halved<3,0>(vr, vi, stb, base_cx, w1); break;
            case 4:     p = obs_full<0>(vr, vi, stb, base_cx, w1);     break;
            case 8 | 0: p = obs_halved<0,1>(vr, vi, stb, base_cx, w1); break;
            case 8 | 1: p = obs_halved<1,1>(vr, vi, stb, base_cx, w1); break;
            case 8 | 2: p = obs_halved<2,1>(vr, vi, stb, base_cx, w1); break;
            case 8 | 3: p = obs_halved<3,1>(vr, vi, stb, base_cx, w1); break;
            default:    p = obs_full<1>(vr, vi, stb, base_cx, w1);     break;
        }
    }
    const int sl = __popc(lane & yzml) & 1;
    return __int_as_float(__float_as_int(p) ^ (sl << 31));
}

// ===================== Kernel A: circuit -> ws (r12 minus obs) ================
__global__ __launch_bounds__(64, 4) void qsa_circ(
    const float* __restrict__ x,
    const float* __restrict__ rx0,
    const float* __restrict__ ry0,
    const float* __restrict__ ry1,
    float2* __restrict__ ws)
{
    __shared__ float2 st[DIM];
    __shared__ float4 s_l1[NQ];
    __shared__ float2 s_l2[NQ];
    const int lane = threadIdx.x;
    const int row  = blockIdx.x;

    if (lane < NQ) {
        float a = 0.5f * rx0[lane], b = 0.5f * ry0[lane];
        float c1 = cosf(a), s1 = sinf(a), c2 = cosf(b), s2 = sinf(b);
        s_l1[lane] = make_float4(c1 * c2, s1 * s2, s2 * c1, c2 * s1);  // A,B,C,D
    } else if (lane < 2 * NQ) {
        float a = 0.5f * ry1[lane - NQ];
        s_l2[lane - NQ] = make_float2(cosf(a), sinf(a));
    }

    float vr[16], vi[16];
    {
        const float* xr = x + (size_t)row * DIM;
        float ssq = 0.f;
        #pragma unroll
        for (int r = 0; r < 16; r++) {
            vr[r] = xr[(r << 6) + lane];
            vi[r] = 0.f;
            ssq += vr[r] * vr[r];
        }
        #pragma unroll
        for (int off = 32; off; off >>= 1) ssq += __shfl_xor(ssq, off, 64);
        const float inv = 1.0f / sqrtf(ssq);
        #pragma unroll
        for (int r = 0; r < 16; r++) vr[r] *= inv;
    }
    __syncthreads();

    #pragma unroll
    for (int j = 0; j < 4; j++) {
        const float4 g = s_l1[j];
        const int m = 1 << (3 - j);
        #pragma unroll
        for (int r = 0; r < 16; r++)
            if (!(r & m)) l1pair(g, vr[r], vi[r], vr[r | m], vi[r | m]);
    }
    lane_gate_l1<5>(s_l1[4], lane, vr, vi);
    lane_gate_l1<4>(s_l1[5], lane, vr, vi);
    lane_gate_l1<3>(s_l1[6], lane, vr, vi);
    lane_gate_l1<2>(s_l1[7], lane, vr, vi);
    lane_gate_l1<1>(s_l1[8], lane, vr, vi);
    lane_gate_l1<0>(s_l1[9], lane, vr, vi);

    #pragma unroll
    for (int r = 0; r < 16; r++) st[(r << 6) | lane] = make_float2(vr[r], vi[r]);
    #pragma unroll
    for (int r = 0; r < 16; r++) {
        int d = (r << 6) | lane;
        int src = (d ^ (d >> 1)) ^ ((d & 1) * 0x300);
        float2 t = st[src];
        vr[r] = t.x; vi[r] = t.y;
    }

    #pragma unroll
    for (int j = 0; j < 4; j++) {
        const float2 g = s_l2[j];
        const int m = 1 << (3 - j);
        #pragma unroll
        for (int r = 0; r < 16; r++)
            if (!(r & m)) l2pair(g, vr[r], vi[r], vr[r | m], vi[r | m]);
    }
    lane_gate_l2<5>(s_l2[4], lane, vr, vi);
    lane_gate_l2<4>(s_l2[5], lane, vr, vi);
    lane_gate_l2<3>(s_l2[6], lane, vr, vi);
    lane_gate_l2<2>(s_l2[7], lane, vr, vi);
    lane_gate_l2<1>(s_l2[8], lane, vr, vi);
    lane_gate_l2<0>(s_l2[9], lane, vr, vi);

    float2* wr_ = ws + (size_t)row * DIM;
    #pragma unroll
    for (int r = 0; r < 16; r++) wr_[(r << 6) | lane] = make_float2(vr[r], vi[r]);
}

// ============ Kernel B: obs from ws, 4 waves/row x 16 obs each ===============
__global__ __launch_bounds__(256, 4) void qsa_obs(
    const float2* __restrict__ ws,
    const int*    __restrict__ op_codes,
    float* __restrict__ out)
{
    __shared__ float2 st[DIM];              // row state (shared by 4 waves)
    __shared__ float  cb[4][64 * 17];       // per-wave transpose-reduce buffer
    __shared__ int4   s_meta[HID];
    const int tid  = threadIdx.x;
    const int lane = tid & 63;
    const int wave = tid >> 6;
    const int row  = blockIdx.x;

    if (tid < HID) s_meta[tid] = make_meta(op_codes, tid);
    {
        const float2* src = ws + (size_t)row * DIM;
        #pragma unroll
        for (int m = 0; m < 4; m++) st[tid + 256 * m] = src[tid + 256 * m];
    }
    __syncthreads();

    float vr[16], vi[16];                   // a-side in regs
    #pragma unroll
    for (int r = 0; r < 16; r++) {
        float2 t = st[(r << 6) | lane];
        vr[r] = t.x; vi[r] = t.y;
    }

    const char* stb = (const char*)st;
    float* cbw = &cb[wave][lane * 17];
    const float* cbr = &cb[wave][(lane >> 4) * (16 * 17) + (lane & 15)];
    #pragma unroll 1
    for (int oo = 0; oo < 16; oo++)
        cbw[oo] = obs_one(s_meta[(wave << 4) + oo], lane, vr, vi, stb);
    // drain (r12 verbatim, single chunk)
    float s0 = 0.f, s1 = 0.f, s2 = 0.f, s3 = 0.f;
    #pragma unroll
    for (int k = 0; k < 16; k += 4) {
        s0 += cbr[(k + 0) * 17];
        s1 += cbr[(k + 1) * 17];
        s2 += cbr[(k + 2) * 17];
        s3 += cbr[(k + 3) * 17];
    }
    float tot = (s0 + s1) + (s2 + s3);      // quarter-sum for obs slot lane&15
    tot += __shfl_xor(tot, 16, 64);
    tot += __shfl_xor(tot, 32, 64);         // full 64-lane sum
    if (lane < 16)
        out[(size_t)row * HID + (wave << 4) + lane] = tot;
}

// =============== Fallback mono-kernel (r12, passed @46.0us) ==================
__global__ __launch_bounds__(64, 4) void qsa_mono(
    const float* __restrict__ x,
    const float* __restrict__ rx0,
    const float* __restrict__ ry0,
    const float* __restrict__ ry1,
    const int*   __restrict__ op_codes,
    float* __restrict__ out)
{
    __shared__ float2 st[DIM];
    __shared__ float  cb[64 * 17];
    __shared__ float4 s_l1[NQ];
    __shared__ float2 s_l2[NQ];
    __shared__ int4   s_meta[HID];
    const int lane = threadIdx.x;
    const int row  = blockIdx.x;

    if (lane < NQ) {
        float a = 0.5f * rx0[lane], b = 0.5f * ry0[lane];
        float c1 = cosf(a), s1 = sinf(a), c2 = cosf(b), s2 = sinf(b);
        s_l1[lane] = make_float4(c1 * c2, s1 * s2, s2 * c1, c2 * s1);
    } else if (lane < 2 * NQ) {
        float a = 0.5f * ry1[lane - NQ];
        s_l2[lane - NQ] = make_float2(cosf(a), sinf(a));
    }
    s_meta[lane] = make_meta(op_codes, lane);

    float vr[16], vi[16];
    {
        const float* xr = x + (size_t)row * DIM;
        float ssq = 0.f;
        #pragma unroll
        for (int r = 0; r < 16; r++) {
            vr[r] = xr[(r << 6) + lane];
            vi[r] = 0.f;
            ssq += vr[r] * vr[r];
        }
        #pragma unroll
        for (int off = 32; off; off >>= 1) ssq += __shfl_xor(ssq, off, 64);
        const float inv = 1.0f / sqrtf(ssq);
        #pragma unroll
        for (int r = 0; r < 16; r++) vr[r] *= inv;
    }
    __syncthreads();

    #pragma unroll
    for (int j = 0; j < 4; j++) {
        const float4 g = s_l1[j];
        const int m = 1 << (3 - j);
        #pragma unroll
        for (int r = 0; r < 16; r++)
            if (!(r & m)) l1pair(g, vr[r], vi[r], vr[r | m], vi[r | m]);
    }
    lane_gate_l1<5>(s_l1[4], lane, vr, vi);
    lane_gate_l1<4>(s_l1[5], lane, vr, vi);
    lane_gate_l1<3>(s_l1[6], lane, vr, vi);
    lane_gate_l1<2>(s_l1[7], lane, vr, vi);
    lane_gate_l1<1>(s_l1[8], lane, vr, vi);
    lane_gate_l1<0>(s_l1[9], lane, vr, vi);

    #pragma unroll
    for (int r = 0; r < 16; r++) st[(r << 6) | lane] = make_float2(vr[r], vi[r]);
    #pragma unroll
    for (int r = 0; r < 16; r++) {
        int d = (r << 6) | lane;
        int src = (d ^ (d >> 1)) ^ ((d & 1) * 0x300);
        float2 t = st[src];
        vr[r] = t.x; vi[r] = t.y;
    }

    #pragma unroll
    for (int j = 0; j < 4; j++) {
        const float2 g = s_l2[j];
        const int m = 1 << (3 - j);
        #pragma unroll
        for (int r = 0; r < 16; r++)
            if (!(r & m)) l2pair(g, vr[r], vi[r], vr[r | m], vi[r | m]);
    }
    lane_gate_l2<5>(s_l2[4], lane, vr, vi);
    lane_gate_l2<4>(s_l2[5], lane, vr, vi);
    lane_gate_l2<3>(s_l2[6], lane, vr, vi);
    lane_gate_l2<2>(s_l2[7], lane, vr, vi);
    lane_gate_l2<1>(s_l2[8], lane, vr, vi);
    lane_gate_l2<0>(s_l2[9], lane, vr, vi);

    #pragma unroll
    for (int r = 0; r < 16; r++) st[(r << 6) | lane] = make_float2(vr[r], vi[r]);

    const char* stb = (const char*)st;
    float* cbw = &cb[lane * 17];
    const float* cbr = &cb[(lane >> 4) * (16 * 17) + (lane & 15)];
    float res = 0.f;
    #pragma unroll 1
    for (int o = 0; o < HID; o++) {
        cbw[o & 15] = obs_one(s_meta[o], lane, vr, vi, stb);
        if ((o & 15) == 15) {
            const int c = o >> 4;
            float s0 = 0.f, s1 = 0.f, s2 = 0.f, s3 = 0.f;
            #pragma unroll
            for (int k = 0; k < 16; k += 4) {
                s0 += cbr[(k + 0) * 17];
                s1 += cbr[(k + 1) * 17];
                s2 += cbr[(k + 2) * 17];
                s3 += cbr[(k + 3) * 17];
            }
            float tot = (s0 + s1) + (s2 + s3);
            tot += __shfl_xor(tot, 16, 64);
            tot += __shfl_xor(tot, 32, 64);
            if ((lane >> 4) == c) res = tot;
        }
    }
    out[(size_t)row * HID + lane] = res;
}

extern "C" void kernel_launch(void* const* d_in, const int* in_sizes, int n_in,
                              void* d_out, int out_size, void* d_ws, size_t ws_size,
                              hipStream_t stream) {
    const float* x   = (const float*)d_in[0];
    const float* rx0 = (const float*)d_in[1];
    const float* ry0 = (const float*)d_in[2];
    const float* ry1 = (const float*)d_in[3];
    const int*   op  = (const int*)d_in[4];
    float* o = (float*)d_out;
    const int rows = in_sizes[0] / DIM;              // B*T = 2048
    const size_t need = (size_t)rows * DIM * sizeof(float2);  // 16 MB
    if (ws_size >= need) {
        float2* ws = (float2*)d_ws;
        qsa_circ<<<rows, 64, 0, stream>>>(x, rx0, ry0, ry1, ws);
        qsa_obs<<<rows, 256, 0, stream>>>(ws, op, o);
    } else {
        qsa_mono<<<rows, 64, 0, stream>>>(x, rx0, ry0, ry1, op, o);
    }
}

// Round 15
// 35.411 us; speedup vs baseline: 1.6703x; 1.3279x over previous
//
#include <hip/hip_runtime.h>
#include <math.h>

#define NQ 10
#define DIM 1024
#define HID 64
#define NT 256

// fused RY*RX 2x2 complex gate (validated r2/r4/r6/r12)
__device__ __forceinline__ void l1pair(float4 g, float& r0, float& i0, float& r1, float& i1) {
    float n0r = g.x * r0 - g.y * i0 - g.z * r1 + g.w * i1;
    float n0i = g.x * i0 + g.y * r0 - g.z * i1 - g.w * r1;
    float n1r = g.z * r0 + g.w * i0 + g.x * r1 + g.y * i1;
    float n1i = g.z * i0 - g.w * r0 + g.x * i1 - g.y * r1;
    r0 = n0r; i0 = n0i; r1 = n1r; i1 = n1i;
}
__device__ __forceinline__ void l2pair(float2 g, float& r0, float& i0, float& r1, float& i1) {
    float n0r = g.x * r0 - g.y * r1, n0i = g.x * i0 - g.y * i1;
    float n1r = g.y * r0 + g.x * r1, n1i = g.y * i0 + g.x * i1;
    r0 = n0r; i0 = n0i; r1 = n1r; i1 = n1i;
}

// ---- obs partial sums (validated r6/r12/r14) ----
template<int HB, int CM>
__device__ __forceinline__ float obs_halved(const float (&vr)[16], const float (&vi)[16],
                                            const char* stb, int base_cx, int w1) {
    float a0 = 0.f, a1 = 0.f;
    #pragma unroll
    for (int idx = 0; idx < 8; idx++) {
        const int lo = idx & ((1 << HB) - 1);
        const int r  = ((idx >> HB) << (HB + 1)) | lo;      // compile-time
        const float2 c = *(const float2*)(stb + (base_cx ^ (r << 9)));
        float t;
        if constexpr (CM) t = vr[r] * c.y - vi[r] * c.x;    // odd nY
        else              t = vr[r] * c.x + vi[r] * c.y;    // even nY
        const int cf = 0x40000000 | (((w1 >> r) & 1) << 31);
        if (idx & 1) a1 = fmaf(__int_as_float(cf), t, a1);
        else         a0 = fmaf(__int_as_float(cf), t, a0);
    }
    return a0 + a1;
}
template<int CM>
__device__ __forceinline__ float obs_full(const float (&vr)[16], const float (&vi)[16],
                                          const char* stb, int base_c, int w1) {
    float a0 = 0.f, a1 = 0.f;
    #pragma unroll
    for (int r = 0; r < 16; r++) {
        const float2 c = *(const float2*)(stb + base_c + (r << 9));
        float t;
        if constexpr (CM) t = vr[r] * c.y - vi[r] * c.x;
        else              t = vr[r] * c.x + vi[r] * c.y;
        const int cf = 0x3F800000 | (((w1 >> r) & 1) << 31);
        if (r & 1) a1 = fmaf(__int_as_float(cf), t, a1);
        else       a0 = fmaf(__int_as_float(cf), t, a0);
    }
    return a0 + a1;
}
__device__ __forceinline__ float obs_diag(const float (&vr)[16], const float (&vi)[16], int w1) {
    float a0 = 0.f, a1 = 0.f;
    #pragma unroll
    for (int r = 0; r < 16; r++) {
        float t = fmaf(vr[r], vr[r], vi[r] * vi[r]);
        const int cf = 0x3F800000 | (((w1 >> r) & 1) << 31);
        if (r & 1) a1 = fmaf(__int_as_float(cf), t, a1);
        else       a0 = fmaf(__int_as_float(cf), t, a0);
    }
    return a0 + a1;
}
__device__ __forceinline__ int4 make_meta(const int* op_codes, int o) {
    int xm = 0, yzm = 0, ny = 0;
    #pragma unroll
    for (int q = 0; q < NQ; q++) {
        int code = op_codes[o * NQ + q];
        int bit  = 1 << (NQ - 1 - q);       // qubit q = element bit 9-q
        if (code == 1) xm |= bit;
        else if (code == 2) { xm |= bit; yzm |= bit; ny++; }
        else if (code == 3) yzm |= bit;
    }
    const int cm = ny & 1, gflip = (ny >> 1) & 1;
    const int yh = yzm >> 6;
    int w1 = 0;
    #pragma unroll
    for (int r = 0; r < 16; r++)
        w1 |= ((__popc(r & yh) & 1) ^ gflip) << r;
    const int xmr = (xm >> 6) & 15;
    int hbc;
    if (xm == 0)      hbc = 5;              // diagonal
    else if (xmr)     hbc = __ffs(xmr) - 1; // halved on reg bit 0..3
    else              hbc = 4;              // lane-only xm: full 16
    return make_int4(xm, yzm & 63, w1, hbc | (cm << 3));
}
__device__ __forceinline__ float obs_one(int4 mt, int lane,
        const float (&vr)[16], const float (&vi)[16], const char* stb) {
    const int xm   = __builtin_amdgcn_readfirstlane(mt.x);
    const int yzml = __builtin_amdgcn_readfirstlane(mt.y);
    const int w1   = __builtin_amdgcn_readfirstlane(mt.z);
    const int knd  = __builtin_amdgcn_readfirstlane(mt.w);
    const int hbc = knd & 7, cm = knd >> 3;
    float p;
    if (hbc == 5) {
        p = obs_diag(vr, vi, w1);
    } else {
        const int xml = xm & 63, xmr = (xm >> 6) & 15;
        const int base_cx = (xmr << 9) | ((lane ^ xml) << 3);
        switch (hbc | (cm << 3)) {
            case 0:     p = obs_halved<0,0>(vr, vi, stb, base_cx, w1); break;
            case 1:     p = obs_halved<1,0>(vr, vi, stb, base_cx, w1); break;
            case 2:     p = obs_halved<2,0>(vr, vi, stb, base_cx, w1); break;
            case 3:     p = obs_halved<3,0>(vr, vi, stb, base_cx, w1); break;
            case 4:     p = obs_full<0>(vr, vi, stb, base_cx, w1);     break;
            case 8 | 0: p = obs_halved<0,1>(vr, vi, stb, base_cx, w1); break;
            case 8 | 1: p = obs_halved<1,1>(vr, vi, stb, base_cx, w1); break;
            case 8 | 2: p = obs_halved<2,1>(vr, vi, stb, base_cx, w1); break;
            case 8 | 3: p = obs_halved<3,1>(vr, vi, stb, base_cx, w1); break;
            default:    p = obs_full<1>(vr, vi, stb, base_cx, w1);     break;
        }
    }
    const int sl = __popc(lane & yzml) & 1;
    return __int_as_float(__float_as_int(p) ^ (sl << 31));
}

// 1 row per 256-thread block (4 waves). Gates: r2's validated multi-wave
// pipeline (4 elems/thread). Obs: r14-B's validated 16-obs/wave phase.
__global__ __launch_bounds__(NT, 2) void qsa_kernel(
    const float* __restrict__ x,
    const float* __restrict__ rx0,
    const float* __restrict__ ry0,
    const float* __restrict__ ry1,
    const int*   __restrict__ op_codes,
    float* __restrict__ out)
{
    __shared__ float2 st[DIM];              // row state (8 KB)
    __shared__ float  cb[4][64 * 17];       // per-wave transpose-reduce buffer
    __shared__ float4 s_l1[NQ];
    __shared__ float2 s_l2[NQ];
    __shared__ int4   s_meta[HID];
    __shared__ float  wsum[4];

    const int tid  = threadIdx.x;
    const int lane = tid & 63;
    const int wave = tid >> 6;
    const int row  = blockIdx.x;            // 2048 blocks

    // ---- setup (r2 layout) ----
    if (tid < NQ) {
        float a = 0.5f * rx0[tid], b = 0.5f * ry0[tid];
        float c1 = cosf(a), s1 = sinf(a), c2 = cosf(b), s2 = sinf(b);
        s_l1[tid] = make_float4(c1 * c2, s1 * s2, s2 * c1, c2 * s1);  // A,B,C,D
    } else if (tid < 2 * NQ) {
        float a = 0.5f * ry1[tid - NQ];
        s_l2[tid - NQ] = make_float2(cosf(a), sinf(a));
    }
    if (tid >= 64 && tid < 64 + HID)
        s_meta[tid - 64] = make_meta(op_codes, tid - 64);

    // ---- load 4 elems/thread + block normalize (r2 verbatim) ----
    float vr[4], vi[4];
    float ssq = 0.f;
    const float* xr = x + (size_t)row * DIM;
    #pragma unroll
    for (int m = 0; m < 4; m++) {
        vr[m] = xr[tid + NT * m];
        vi[m] = 0.f;
        ssq += vr[m] * vr[m];
    }
    #pragma unroll
    for (int off = 32; off; off >>= 1) ssq += __shfl_xor(ssq, off, 64);
    if (lane == 0) wsum[wave] = ssq;
    __syncthreads();                                     // B0 (also fences tables)
    {
        float inv = 1.0f / sqrtf(wsum[0] + wsum[1] + wsum[2] + wsum[3]);
        #pragma unroll
        for (int m = 0; m < 4; m++) vr[m] *= inv;
    }

    // ---- layer 1 (r2 verbatim): bits 9,8 in-reg; 7,6 LDS 4x4; 5..0 shuffles ----
    {
        float4 g0 = s_l1[0];
        l1pair(g0, vr[0], vi[0], vr[2], vi[2]);
        l1pair(g0, vr[1], vi[1], vr[3], vi[3]);
        float4 g1 = s_l1[1];
        l1pair(g1, vr[0], vi[0], vr[1], vi[1]);
        l1pair(g1, vr[2], vi[2], vr[3], vi[3]);
    }
    #pragma unroll
    for (int m = 0; m < 4; m++) st[tid + NT * m] = make_float2(vr[m], vi[m]);
    __syncthreads();                                     // B1
    {
        int base = lane | (wave << 8);
        float2 w00 = st[base], w01 = st[base | 64], w10 = st[base | 128], w11 = st[base | 192];
        float4 g2 = s_l1[2], g3 = s_l1[3];
        l1pair(g2, w00.x, w00.y, w10.x, w10.y);
        l1pair(g2, w01.x, w01.y, w11.x, w11.y);
        l1pair(g3, w00.x, w00.y, w01.x, w01.y);
        l1pair(g3, w10.x, w10.y, w11.x, w11.y);
        st[base] = w00; st[base | 64] = w01; st[base | 128] = w10; st[base | 192] = w11;
    }
    __syncthreads();                                     // B2
    #pragma unroll
    for (int m = 0; m < 4; m++) { float2 t = st[tid + NT * m]; vr[m] = t.x; vi[m] = t.y; }
    #pragma unroll
    for (int j = 4; j < NQ; j++) {                       // p=5..0: shuffle gates
        const int p = NQ - 1 - j;
        const int msk = 1 << p;
        float4 g = s_l1[j];
        float fsb = ((tid >> p) & 1) ? 1.f : -1.f;
        float Bs = fsb * g.y, Cs = fsb * g.z;
        #pragma unroll
        for (int m = 0; m < 4; m++) {
            float ur = __shfl_xor(vr[m], msk, 64);
            float ui = __shfl_xor(vi[m], msk, 64);
            float nr = g.x * vr[m] + Bs * vi[m] + Cs * ur + g.w * ui;
            float ni = g.x * vi[m] - Bs * vr[m] + Cs * ui - g.w * ur;
            vr[m] = nr; vi[m] = ni;
        }
    }

    // ---- CNOT ring: composed permutation gather (r2 verbatim) ----
    #pragma unroll
    for (int m = 0; m < 4; m++) st[tid + NT * m] = make_float2(vr[m], vi[m]);
    __syncthreads();                                     // B3
    #pragma unroll
    for (int m = 0; m < 4; m++) {
        int d = tid + NT * m;
        int src = (d ^ (d >> 1)) ^ ((d & 1) * 0x300);
        float2 t = st[src];
        vr[m] = t.x; vi[m] = t.y;
    }
    __syncthreads();                                     // B4

    // ---- layer 2 (r2 verbatim) ----
    {
        float2 g0 = s_l2[0];
        l2pair(g0, vr[0], vi[0], vr[2], vi[2]);
        l2pair(g0, vr[1], vi[1], vr[3], vi[3]);
        float2 g1 = s_l2[1];
        l2pair(g1, vr[0], vi[0], vr[1], vi[1]);
        l2pair(g1, vr[2], vi[2], vr[3], vi[3]);
    }
    #pragma unroll
    for (int m = 0; m < 4; m++) st[tid + NT * m] = make_float2(vr[m], vi[m]);
    __syncthreads();                                     // B5
    {
        int base = lane | (wave << 8);
        float2 w00 = st[base], w01 = st[base | 64], w10 = st[base | 128], w11 = st[base | 192];
        float2 g2 = s_l2[2], g3 = s_l2[3];
        l2pair(g2, w00.x, w00.y, w10.x, w10.y);
        l2pair(g2, w01.x, w01.y, w11.x, w11.y);
        l2pair(g3, w00.x, w00.y, w01.x, w01.y);
        l2pair(g3, w10.x, w10.y, w11.x, w11.y);
        st[base] = w00; st[base | 64] = w01; st[base | 128] = w10; st[base | 192] = w11;
    }
    __syncthreads();                                     // B6
    #pragma unroll
    for (int m = 0; m < 4; m++) { float2 t = st[tid + NT * m]; vr[m] = t.x; vi[m] = t.y; }
    #pragma unroll
    for (int j = 4; j < NQ; j++) {
        const int p = NQ - 1 - j;
        const int msk = 1 << p;
        float2 g = s_l2[j];
        float fsb = ((tid >> p) & 1) ? 1.f : -1.f;
        float ssf = fsb * g.y;
        #pragma unroll
        for (int m = 0; m < 4; m++) {
            float ur = __shfl_xor(vr[m], msk, 64);
            float ui = __shfl_xor(vi[m], msk, 64);
            vr[m] = g.x * vr[m] + ssf * ur;
            vi[m] = g.x * vi[m] + ssf * ui;
        }
    }
    #pragma unroll
    for (int m = 0; m < 4; m++) st[tid + NT * m] = make_float2(vr[m], vi[m]);
    __syncthreads();                                     // B7: final state ready

    // ---- obs phase (r14-B verbatim): wave owns obs wave*16..wave*16+15 ----
    float vra[16], via[16];                              // a-side fragment
    #pragma unroll
    for (int r = 0; r < 16; r++) {
        float2 t = st[(r << 6) | lane];
        vra[r] = t.x; via[r] = t.y;
    }
    const char* stb = (const char*)st;
    float* cbw = &cb[wave][lane * 17];
    const float* cbr = &cb[wave][(lane >> 4) * (16 * 17) + (lane & 15)];
    #pragma unroll 1
    for (int oo = 0; oo < 16; oo++)
        cbw[oo] = obs_one(s_meta[(wave << 4) + oo], lane, vra, via, stb);
    float s0 = 0.f, s1 = 0.f, s2 = 0.f, s3 = 0.f;
    #pragma unroll
    for (int k = 0; k < 16; k += 4) {
        s0 += cbr[(k + 0) * 17];
        s1 += cbr[(k + 1) * 17];
        s2 += cbr[(k + 2) * 17];
        s3 += cbr[(k + 3) * 17];
    }
    float tot = (s0 + s1) + (s2 + s3);                   // quarter-sum, obs lane&15
    tot += __shfl_xor(tot, 16, 64);
    tot += __shfl_xor(tot, 32, 64);                      // full 64-lane sum
    if (lane < 16)
        out[(size_t)row * HID + (wave << 4) + lane] = tot;
}

extern "C" void kernel_launch(void* const* d_in, const int* in_sizes, int n_in,
                              void* d_out, int out_size, void* d_ws, size_t ws_size,
                              hipStream_t stream) {
    const float* x   = (const float*)d_in[0];
    const float* rx0 = (const float*)d_in[1];
    const float* ry0 = (const float*)d_in[2];
    const float* ry1 = (const float*)d_in[3];
    const int*   op  = (const int*)d_in[4];
    float* o = (float*)d_out;
    const int rows = in_sizes[0] / DIM;    // B*T = 2048
    qsa_kernel<<<rows, NT, 0, stream>>>(x, rx0, ry0, ry1, op, o);
}

// Round 16
// 33.588 us; speedup vs baseline: 1.7609x; 1.0543x over previous
//
#include <hip/hip_runtime.h>
#include <math.h>

#define NQ 10
#define DIM 1024
#define HID 64
#define NT 256

template<int CTRL>
__device__ __forceinline__ float fdpp(float v) {
    return __int_as_float(__builtin_amdgcn_update_dpp(
        0, __float_as_int(v), CTRL, 0xF, 0xF, true));
}

// fused RY*RX 2x2 complex gate (validated r2/r4/r6/r12/r15)
__device__ __forceinline__ void l1pair(float4 g, float& r0, float& i0, float& r1, float& i1) {
    float n0r = g.x * r0 - g.y * i0 - g.z * r1 + g.w * i1;
    float n0i = g.x * i0 + g.y * r0 - g.z * i1 - g.w * r1;
    float n1r = g.z * r0 + g.w * i0 + g.x * r1 + g.y * i1;
    float n1i = g.z * i0 - g.w * r0 + g.x * i1 - g.y * r1;
    r0 = n0r; i0 = n0i; r1 = n1r; i1 = n1i;
}
__device__ __forceinline__ void l2pair(float2 g, float& r0, float& i0, float& r1, float& i1) {
    float n0r = g.x * r0 - g.y * r1, n0i = g.x * i0 - g.y * i1;
    float n1r = g.y * r0 + g.x * r1, n1i = g.y * i0 + g.x * i1;
    r0 = n0r; i0 = n0i; r1 = n1r; i1 = n1i;
}

// cross-lane fetch of v from lane^(1<<P): DPP for P=0,1 (exact quad_perm XOR,
// VALU pipe — r12-validated), shfl for P>=2 (DS/permlane).
template<int P>
__device__ __forceinline__ float xl(float v) {
    if constexpr (P == 0)      return fdpp<0xB1>(v);   // lane^1
    else if constexpr (P == 1) return fdpp<0x4E>(v);   // lane^2
    else                       return __shfl_xor(v, 1 << P, 64);
}

// shuffle-gate on tid-bit P (element bit P), 4-reg arrays (r2 math, validated)
template<int P>
__device__ __forceinline__ void gate4_l1(float4 g, int tid, float (&vr)[4], float (&vi)[4]) {
    const float fsb = ((tid >> P) & 1) ? 1.f : -1.f;
    const float Bs = fsb * g.y, Cs = fsb * g.z;
    #pragma unroll
    for (int m = 0; m < 4; m++) {
        float ur = xl<P>(vr[m]);
        float ui = xl<P>(vi[m]);
        float nr = g.x * vr[m] + Bs * vi[m] + Cs * ur + g.w * ui;
        float ni = g.x * vi[m] - Bs * vr[m] + Cs * ui - g.w * ur;
        vr[m] = nr; vi[m] = ni;
    }
}
template<int P>
__device__ __forceinline__ void gate4_l2(float2 g, int tid, float (&vr)[4], float (&vi)[4]) {
    const float fsb = ((tid >> P) & 1) ? 1.f : -1.f;
    const float ssf = fsb * g.y;
    #pragma unroll
    for (int m = 0; m < 4; m++) {
        float ur = xl<P>(vr[m]);
        float ui = xl<P>(vi[m]);
        vr[m] = g.x * vr[m] + ssf * ur;
        vi[m] = g.x * vi[m] + ssf * ui;
    }
}

// ---- obs partial sums (validated r6/r12/r14/r15) ----
template<int HB, int CM>
__device__ __forceinline__ float obs_halved(const float (&vr)[16], const float (&vi)[16],
                                            const char* stb, int base_cx, int w1) {
    float a0 = 0.f, a1 = 0.f;
    #pragma unroll
    for (int idx = 0; idx < 8; idx++) {
        const int lo = idx & ((1 << HB) - 1);
        const int r  = ((idx >> HB) << (HB + 1)) | lo;      // compile-time
        const float2 c = *(const float2*)(stb + (base_cx ^ (r << 9)));
        float t;
        if constexpr (CM) t = vr[r] * c.y - vi[r] * c.x;    // odd nY
        else              t = vr[r] * c.x + vi[r] * c.y;    // even nY
        const int cf = 0x40000000 | (((w1 >> r) & 1) << 31);
        if (idx & 1) a1 = fmaf(__int_as_float(cf), t, a1);
        else         a0 = fmaf(__int_as_float(cf), t, a0);
    }
    return a0 + a1;
}
template<int CM>
__device__ __forceinline__ float obs_full(const float (&vr)[16], const float (&vi)[16],
                                          const char* stb, int base_c, int w1) {
    float a0 = 0.f, a1 = 0.f;
    #pragma unroll
    for (int r = 0; r < 16; r++) {
        const float2 c = *(const float2*)(stb + base_c + (r << 9));
        float t;
        if constexpr (CM) t = vr[r] * c.y - vi[r] * c.x;
        else              t = vr[r] * c.x + vi[r] * c.y;
        const int cf = 0x3F800000 | (((w1 >> r) & 1) << 31);
        if (r & 1) a1 = fmaf(__int_as_float(cf), t, a1);
        else       a0 = fmaf(__int_as_float(cf), t, a0);
    }
    return a0 + a1;
}
__device__ __forceinline__ float obs_diag(const float (&vr)[16], const float (&vi)[16], int w1) {
    float a0 = 0.f, a1 = 0.f;
    #pragma unroll
    for (int r = 0; r < 16; r++) {
        float t = fmaf(vr[r], vr[r], vi[r] * vi[r]);
        const int cf = 0x3F800000 | (((w1 >> r) & 1) << 31);
        if (r & 1) a1 = fmaf(__int_as_float(cf), t, a1);
        else       a0 = fmaf(__int_as_float(cf), t, a0);
    }
    return a0 + a1;
}
__device__ __forceinline__ int4 make_meta(const int* op_codes, int o) {
    int xm = 0, yzm = 0, ny = 0;
    #pragma unroll
    for (int q = 0; q < NQ; q++) {
        int code = op_codes[o * NQ + q];
        int bit  = 1 << (NQ - 1 - q);       // qubit q = element bit 9-q
        if (code == 1) xm |= bit;
        else if (code == 2) { xm |= bit; yzm |= bit; ny++; }
        else if (code == 3) yzm |= bit;
    }
    const int cm = ny & 1, gflip = (ny >> 1) & 1;
    const int yh = yzm >> 6;
    int w1 = 0;
    #pragma unroll
    for (int r = 0; r < 16; r++)
        w1 |= ((__popc(r & yh) & 1) ^ gflip) << r;
    const int xmr = (xm >> 6) & 15;
    int hbc;
    if (xm == 0)      hbc = 5;              // diagonal
    else if (xmr)     hbc = __ffs(xmr) - 1; // halved on reg bit 0..3
    else              hbc = 4;              // lane-only xm: full 16
    return make_int4(xm, yzm & 63, w1, hbc | (cm << 3));
}
__device__ __forceinline__ float obs_one(int4 mt, int lane,
        const float (&vr)[16], const float (&vi)[16], const char* stb) {
    const int xm   = __builtin_amdgcn_readfirstlane(mt.x);
    const int yzml = __builtin_amdgcn_readfirstlane(mt.y);
    const int w1   = __builtin_amdgcn_readfirstlane(mt.z);
    const int knd  = __builtin_amdgcn_readfirstlane(mt.w);
    const int hbc = knd & 7, cm = knd >> 3;
    float p;
    if (hbc == 5) {
        p = obs_diag(vr, vi, w1);
    } else {
        const int xml = xm & 63, xmr = (xm >> 6) & 15;
        const int base_cx = (xmr << 9) | ((lane ^ xml) << 3);
        switch (hbc | (cm << 3)) {
            case 0:     p = obs_halved<0,0>(vr, vi, stb, base_cx, w1); break;
            case 1:     p = obs_halved<1,0>(vr, vi, stb, base_cx, w1); break;
            case 2:     p = obs_halved<2,0>(vr, vi, stb, base_cx, w1); break;
            case 3:     p = obs_halved<3,0>(vr, vi, stb, base_cx, w1); break;
            case 4:     p = obs_full<0>(vr, vi, stb, base_cx, w1);     break;
            case 8 | 0: p = obs_halved<0,1>(vr, vi, stb, base_cx, w1); break;
            case 8 | 1: p = obs_halved<1,1>(vr, vi, stb, base_cx, w1); break;
            case 8 | 2: p = obs_halved<2,1>(vr, vi, stb, base_cx, w1); break;
            case 8 | 3: p = obs_halved<3,1>(vr, vi, stb, base_cx, w1); break;
            default:    p = obs_full<1>(vr, vi, stb, base_cx, w1);     break;
        }
    }
    const int sl = __popc(lane & yzml) & 1;
    return __int_as_float(__float_as_int(p) ^ (sl << 31));
}

// 1 row per 256-thread block (4 waves). Gates: r2 pipeline; obs: r14-B phase.
__global__ __launch_bounds__(NT, 2) void qsa_kernel(
    const float* __restrict__ x,
    const float* __restrict__ rx0,
    const float* __restrict__ ry0,
    const float* __restrict__ ry1,
    const int*   __restrict__ op_codes,
    float* __restrict__ out)
{
    __shared__ float2 st[DIM];              // row state (8 KB)
    __shared__ float  cb[4][64 * 17];       // per-wave transpose-reduce buffer
    __shared__ float4 s_l1[NQ];
    __shared__ float2 s_l2[NQ];
    __shared__ int4   s_meta[HID];
    __shared__ float  wsum[4];

    const int tid  = threadIdx.x;
    const int lane = tid & 63;
    const int wave = tid >> 6;
    const int row  = blockIdx.x;            // 2048 blocks

    // ---- setup (r15 verbatim) ----
    if (tid < NQ) {
        float a = 0.5f * rx0[tid], b = 0.5f * ry0[tid];
        float c1 = cosf(a), s1 = sinf(a), c2 = cosf(b), s2 = sinf(b);
        s_l1[tid] = make_float4(c1 * c2, s1 * s2, s2 * c1, c2 * s1);  // A,B,C,D
    } else if (tid < 2 * NQ) {
        float a = 0.5f * ry1[tid - NQ];
        s_l2[tid - NQ] = make_float2(cosf(a), sinf(a));
    }
    if (tid >= 64 && tid < 64 + HID)
        s_meta[tid - 64] = make_meta(op_codes, tid - 64);

    // ---- load 4 elems/thread + block normalize ----
    float vr[4], vi[4];
    float ssq = 0.f;
    const float* xr = x + (size_t)row * DIM;
    #pragma unroll
    for (int m = 0; m < 4; m++) {
        vr[m] = xr[tid + NT * m];
        vi[m] = 0.f;
        ssq += vr[m] * vr[m];
    }
    #pragma unroll
    for (int off = 32; off; off >>= 1) ssq += __shfl_xor(ssq, off, 64);
    if (lane == 0) wsum[wave] = ssq;
    __syncthreads();                                     // B0 (also fences tables)
    {
        float inv = 1.0f / sqrtf(wsum[0] + wsum[1] + wsum[2] + wsum[3]);
        #pragma unroll
        for (int m = 0; m < 4; m++) vr[m] *= inv;
    }

    // ---- layer 1: bits 9,8 in-reg; 7,6 LDS 4x4; 5..0 shuffle/DPP gates ----
    {
        float4 g0 = s_l1[0];
        l1pair(g0, vr[0], vi[0], vr[2], vi[2]);
        l1pair(g0, vr[1], vi[1], vr[3], vi[3]);
        float4 g1 = s_l1[1];
        l1pair(g1, vr[0], vi[0], vr[1], vi[1]);
        l1pair(g1, vr[2], vi[2], vr[3], vi[3]);
    }
    #pragma unroll
    for (int m = 0; m < 4; m++) st[tid + NT * m] = make_float2(vr[m], vi[m]);
    __syncthreads();                                     // B1
    {
        int base = lane | (wave << 8);
        float2 w00 = st[base], w01 = st[base | 64], w10 = st[base | 128], w11 = st[base | 192];
        float4 g2 = s_l1[2], g3 = s_l1[3];
        l1pair(g2, w00.x, w00.y, w10.x, w10.y);
        l1pair(g2, w01.x, w01.y, w11.x, w11.y);
        l1pair(g3, w00.x, w00.y, w01.x, w01.y);
        l1pair(g3, w10.x, w10.y, w11.x, w11.y);
        st[base] = w00; st[base | 64] = w01; st[base | 128] = w10; st[base | 192] = w11;
    }
    __syncthreads();                                     // B2
    #pragma unroll
    for (int m = 0; m < 4; m++) { float2 t = st[tid + NT * m]; vr[m] = t.x; vi[m] = t.y; }
    gate4_l1<5>(s_l1[4], tid, vr, vi);
    gate4_l1<4>(s_l1[5], tid, vr, vi);
    gate4_l1<3>(s_l1[6], tid, vr, vi);
    gate4_l1<2>(s_l1[7], tid, vr, vi);
    gate4_l1<1>(s_l1[8], tid, vr, vi);
    gate4_l1<0>(s_l1[9], tid, vr, vi);

    // ---- CNOT ring: composed permutation gather ----
    #pragma unroll
    for (int m = 0; m < 4; m++) st[tid + NT * m] = make_float2(vr[m], vi[m]);
    __syncthreads();                                     // B3
    #pragma unroll
    for (int m = 0; m < 4; m++) {
        int d = tid + NT * m;
        int src = (d ^ (d >> 1)) ^ ((d & 1) * 0x300);
        float2 t = st[src];
        vr[m] = t.x; vi[m] = t.y;
    }
    __syncthreads();                                     // B4

    // ---- layer 2 (RY) ----
    {
        float2 g0 = s_l2[0];
        l2pair(g0, vr[0], vi[0], vr[2], vi[2]);
        l2pair(g0, vr[1], vi[1], vr[3], vi[3]);
        float2 g1 = s_l2[1];
        l2pair(g1, vr[0], vi[0], vr[1], vi[1]);
        l2pair(g1, vr[2], vi[2], vr[3], vi[3]);
    }
    #pragma unroll
    for (int m = 0; m < 4; m++) st[tid + NT * m] = make_float2(vr[m], vi[m]);
    __syncthreads();                                     // B5
    {
        int base = lane | (wave << 8);
        float2 w00 = st[base], w01 = st[base | 64], w10 = st[base | 128], w11 = st[base | 192];
        float2 g2 = s_l2[2], g3 = s_l2[3];
        l2pair(g2, w00.x, w00.y, w10.x, w10.y);
        l2pair(g2, w01.x, w01.y, w11.x, w11.y);
        l2pair(g3, w00.x, w00.y, w01.x, w01.y);
        l2pair(g3, w10.x, w10.y, w11.x, w11.y);
        st[base] = w00; st[base | 64] = w01; st[base | 128] = w10; st[base | 192] = w11;
    }
    __syncthreads();                                     // B6
    #pragma unroll
    for (int m = 0; m < 4; m++) { float2 t = st[tid + NT * m]; vr[m] = t.x; vi[m] = t.y; }
    gate4_l2<5>(s_l2[4], tid, vr, vi);
    gate4_l2<4>(s_l2[5], tid, vr, vi);
    gate4_l2<3>(s_l2[6], tid, vr, vi);
    gate4_l2<2>(s_l2[7], tid, vr, vi);
    gate4_l2<1>(s_l2[8], tid, vr, vi);
    gate4_l2<0>(s_l2[9], tid, vr, vi);
    #pragma unroll
    for (int m = 0; m < 4; m++) st[tid + NT * m] = make_float2(vr[m], vi[m]);
    __syncthreads();                                     // B7: final state ready

    // ---- obs phase: wave owns obs wave*16..wave*16+15 (unroll 2 for MLP) ----
    float vra[16], via[16];                              // a-side fragment
    #pragma unroll
    for (int r = 0; r < 16; r++) {
        float2 t = st[(r << 6) | lane];
        vra[r] = t.x; via[r] = t.y;
    }
    const char* stb = (const char*)st;
    float* cbw = &cb[wave][lane * 17];
    const float* cbr = &cb[wave][(lane >> 4) * (16 * 17) + (lane & 15)];
    #pragma unroll 2
    for (int oo = 0; oo < 16; oo++)
        cbw[oo] = obs_one(s_meta[(wave << 4) + oo], lane, vra, via, stb);
    float s0 = 0.f, s1 = 0.f, s2 = 0.f, s3 = 0.f;
    #pragma unroll
    for (int k = 0; k < 16; k += 4) {
        s0 += cbr[(k + 0) * 17];
        s1 += cbr[(k + 1) * 17];
        s2 += cbr[(k + 2) * 17];
        s3 += cbr[(k + 3) * 17];
    }
    float tot = (s0 + s1) + (s2 + s3);                   // quarter-sum, obs lane&15
    tot += __shfl_xor(tot, 16, 64);
    tot += __shfl_xor(tot, 32, 64);                      // full 64-lane sum
    if (lane < 16)
        out[(size_t)row * HID + (wave << 4) + lane] = tot;
}

extern "C" void kernel_launch(void* const* d_in, const int* in_sizes, int n_in,
                              void* d_out, int out_size, void* d_ws, size_t ws_size,
                              hipStream_t stream) {
    const float* x   = (const float*)d_in[0];
    const float* rx0 = (const float*)d_in[1];
    const float* ry0 = (const float*)d_in[2];
    const float* ry1 = (const float*)d_in[3];
    const int*   op  = (const int*)d_in[4];
    float* o = (float*)d_out;
    const int rows = in_sizes[0] / DIM;    // B*T = 2048
    qsa_kernel<<<rows, NT, 0, stream>>>(x, rx0, ry0, ry1, op, o);
}